// Round 7
// baseline (168.378 us; speedup 1.0000x reference)
//
#include <hip/hip_runtime.h>
#include <hip/hip_bf16.h>
#include <math.h>

typedef short short4v __attribute__((ext_vector_type(4)));
typedef short short8 __attribute__((ext_vector_type(8)));
typedef __bf16 bf16x8 __attribute__((ext_vector_type(8)));
typedef float f32x4 __attribute__((ext_vector_type(4)));

#define SEQ 4096
#define QK_SCALE 0.18033688011112042f  /* (1/8) * log2(e) */

__device__ __forceinline__ short f2bf(float f) {
    __bf16 h = (__bf16)f;
    return __builtin_bit_cast(short, h);
}

__device__ __forceinline__ float exp2a(float x) {  // raw v_exp_f32 (2^x)
    float r;
    asm("v_exp_f32 %0, %1" : "=v"(r) : "v"(x));
    return r;
}

__device__ __forceinline__ f32x4 mfma16(short8 a, short8 b, f32x4 c) {
    return __builtin_amdgcn_mfma_f32_16x16x32_bf16(
        __builtin_bit_cast(bf16x8, a), __builtin_bit_cast(bf16x8, b), c, 0, 0, 0);
}

// ---- kernel 1: W fp32 -> bf16, pre-fragmented for MFMA B-operand. ----
__global__ __launch_bounds__(256) void wconv_kernel(
    const float* __restrict__ wq, const float* __restrict__ wk,
    const float* __restrict__ wv, short* __restrict__ out) {
  int i = blockIdx.x * 256 + threadIdx.x;
  const int j = i & 7, lane = (i >> 3) & 63, nb = (i >> 9) & 3;
  const int t = (i >> 11) & 15, mat = i >> 15;
  const int g = lane >> 4, r = lane & 15;
  const int src = (nb * 16 + r) * 512 + t * 32 + g * 8 + j;
  float v;
  if (mat == 0)      v = wq[src] * QK_SCALE;
  else if (mat == 1) v = wk[src];
  else               v = wv[src];
  out[i] = f2bf(v);
}

// ---- kernel 2: QKV projection (unchanged; ~12-18 us, not the bottleneck). ----
__global__ __launch_bounds__(256) void proj_kernel(
    const float* __restrict__ x, const short* __restrict__ wf,
    short* __restrict__ Qs, short* __restrict__ Ks, short* __restrict__ Vt) {
  __shared__ short stg[4][16][72];
  const int bb = blockIdx.x;
  const int mat = bb >> 8, rb = bb & 255;
  const int wave = threadIdx.x >> 6, lane = threadIdx.x & 63;
  const int g = lane >> 4, r = lane & 15;
  const int rbase = rb * 64 + wave * 16;
  const short* wbase = wf + (size_t)mat * 32768;

  f32x4 acc[4];
#pragma unroll
  for (int nb = 0; nb < 4; ++nb) acc[nb] = (f32x4)0.f;

  const float* xp = x + (size_t)(rbase + r) * 512;
#pragma unroll 4
  for (int k0 = 0; k0 < 512; k0 += 32) {
    const int kb = k0 + g * 8;
    f32x4 f0 = *(const f32x4*)(xp + kb);
    f32x4 f1 = *(const f32x4*)(xp + kb + 4);
    short8 a;
    a[0] = f2bf(f0[0]); a[1] = f2bf(f0[1]); a[2] = f2bf(f0[2]); a[3] = f2bf(f0[3]);
    a[4] = f2bf(f1[0]); a[5] = f2bf(f1[1]); a[6] = f2bf(f1[2]); a[7] = f2bf(f1[3]);
    const short* wp = wbase + ((size_t)(k0 >> 5) * 4 * 64 + lane) * 8;
#pragma unroll
    for (int nb = 0; nb < 4; ++nb) {
      short8 bq = *(const short8*)(wp + nb * 512);
      acc[nb] = mfma16(a, bq, acc[nb]);
    }
  }

#pragma unroll
  for (int nb = 0; nb < 4; ++nb) {
#pragma unroll
    for (int reg = 0; reg < 4; ++reg)
      stg[wave][g * 4 + reg][nb * 16 + r] = f2bf(acc[nb][reg]);
  }
  if (mat < 2) {
    short* dst = (mat == 0) ? Qs : Ks;
    const int orow = lane >> 2, ob = lane & 3;
    short8 v0 = *(const short8*)&stg[wave][orow][ob * 8];
    short8 v1 = *(const short8*)&stg[wave][orow][ob * 8 + 32];
    *(short8*)(dst + (size_t)(rbase + orow) * 64 + ob * 8) = v0;
    *(short8*)(dst + (size_t)(rbase + orow) * 64 + ob * 8 + 32) = v1;
  } else {
    const int b = rbase >> 12, sb = rbase & 4095;
    short* vrow = Vt + ((size_t)(b * 64 + lane)) * SEQ + sb;
    short8 v0, v1;
#pragma unroll
    for (int j = 0; j < 8; ++j) v0[j] = stg[wave][j][lane];
#pragma unroll
    for (int j = 0; j < 8; ++j) v1[j] = stg[wave][j + 8][lane];
    *(short8*)(vrow) = v0;
    *(short8*)(vrow + 8) = v1;
  }
}

// ---- kernel 3: flash attention, causal, swapped-operand MFMA.
// 512 blocks x 512 thr (8 waves): 32 q-rows/block, 8-way KV split.
// Per-wave LDS region (8960 B): ptq (P staging, 5120 B, loop-live) unions
// po/pm/pl (partials, written after loop). Balanced t<->CU mapping. ----
#define REGION 8960
__global__ __launch_bounds__(512, 4) void attn_kernel(
    const short* __restrict__ Qs, const short* __restrict__ Ks,
    const short* __restrict__ Vt, float* __restrict__ out) {
  __shared__ __align__(16) char smem[8][REGION];
  const int blk = blockIdx.x;
  const int c = blk & 255, k = blk >> 8;
  // balanced: co-resident blocks (same c, k=0/1) have t sums == 127
  const int t = k ? (c >> 1) : (127 - (c >> 1));
  const int b = (k << 1) | (c & 1);
  const int wave = threadIdx.x >> 6, lane = threadIdx.x & 63;
  const int g = lane >> 4, r = lane & 15;
  const int qbase = t * 32;
  const short* Qb = Qs + (size_t)b * (SEQ * 64);
  const short* Kb = Ks + (size_t)b * (SEQ * 64);
  const short* Vb = Vt + (size_t)b * (64 * SEQ);

  short* ptq_w = (short*)smem[wave];          // [2][16][80] shorts
  float* po_w  = (float*)smem[wave];          // [32][68] floats (after loop)
  float* pm_w  = (float*)(smem[wave] + 8704); // [32]
  float* pl_w  = (float*)(smem[wave] + 8832); // [32]

  // Q fragments (B-operand: Q[q=r][k]) for both rowblocks
  short8 qf[2][2];
#pragma unroll
  for (int rb = 0; rb < 2; ++rb) {
    const int qoff = (qbase + rb * 16 + r) * 64 + g * 8;
    qf[rb][0] = *(const short8*)(Qb + qoff);
    qf[rb][1] = *(const short8*)(Qb + qoff + 32);
  }

  f32x4 o[2][4];
  float m[2] = {-1e30f, -1e30f}, l[2] = {0.f, 0.f};
#pragma unroll
  for (int rb = 0; rb < 2; ++rb)
#pragma unroll
    for (int nb = 0; nb < 4; ++nb) o[rb][nb] = (f32x4)0.f;

  for (int s0 = wave * 64; s0 <= qbase + 31; s0 += 512) {
    // K fragments (A-operand: K[s][k]), shared by both rowblocks
    short8 kf0[4], kf1[4];
#pragma unroll
    for (int nc = 0; nc < 4; ++nc) {
      const int koff = (s0 + nc * 16 + r) * 64 + g * 8;
      kf0[nc] = *(const short8*)(Kb + koff);
      kf1[nc] = *(const short8*)(Kb + koff + 32);
    }
    // V fragments hoisted (A-operand: Vt[d][s]), shared
    short8 vv0[4], vv1[4];
#pragma unroll
    for (int nb = 0; nb < 4; ++nb) {
      const int voff = (nb * 16 + r) * SEQ + s0 + g * 8;
      vv0[nb] = *(const short8*)(Vb + voff);
      vv1[nb] = *(const short8*)(Vb + voff + 32);
    }

#pragma unroll
    for (int rb = 0; rb < 2; ++rb) {
      // ---- S^T: D[row=s][col=q]; lane: q=r, s=s0+nc*16+g*4+reg ----
      f32x4 sc[4];
#pragma unroll
      for (int nc = 0; nc < 4; ++nc) {
        sc[nc] = (f32x4)0.f;
        sc[nc] = mfma16(kf0[nc], qf[rb][0], sc[nc]);
        sc[nc] = mfma16(kf1[nc], qf[rb][1], sc[nc]);
      }
      const int q = qbase + rb * 16 + r;
      if (s0 + 63 > q) {
#pragma unroll
        for (int nc = 0; nc < 4; ++nc) {
          const int sbase = s0 + nc * 16 + g * 4;
#pragma unroll
          for (int reg = 0; reg < 4; ++reg)
            if (sbase + reg > q) sc[nc][reg] = -1e30f;
        }
      }
      // ---- online softmax: lane-local row + 2 shfl ----
      float mx = fmaxf(fmaxf(sc[0][0], sc[0][1]), fmaxf(sc[0][2], sc[0][3]));
#pragma unroll
      for (int nc = 1; nc < 4; ++nc)
        mx = fmaxf(mx, fmaxf(fmaxf(sc[nc][0], sc[nc][1]), fmaxf(sc[nc][2], sc[nc][3])));
      mx = fmaxf(mx, __shfl_xor(mx, 16));
      mx = fmaxf(mx, __shfl_xor(mx, 32));
      const float mn = fmaxf(m[rb], mx);
      const float fac = exp2a(m[rb] - mn);
      m[rb] = mn;
      float rs = 0.f;
#pragma unroll
      for (int nc = 0; nc < 4; ++nc) {
#pragma unroll
        for (int reg = 0; reg < 4; ++reg) {
          const float p = exp2a(sc[nc][reg] - mn);
          sc[nc][reg] = p;
          rs += p;
        }
      }
      rs += __shfl_xor(rs, 16);
      rs += __shfl_xor(rs, 32);
      l[rb] = l[rb] * fac + rs;
#pragma unroll
      for (int nb = 0; nb < 4; ++nb) o[rb][nb] *= fac;
      // ---- P^T -> LDS [q][s] (wave-local) ----
#pragma unroll
      for (int nc = 0; nc < 4; ++nc) {
        short4v p4;
        p4[0] = f2bf(sc[nc][0]); p4[1] = f2bf(sc[nc][1]);
        p4[2] = f2bf(sc[nc][2]); p4[3] = f2bf(sc[nc][3]);
        *(short4v*)(ptq_w + rb * 1280 + r * 80 + nc * 16 + g * 4) = p4;
      }
      // ---- PV: O^T[d][q] += V^T[d][s] * P^T[s][q] ----
      const short8 pa0 = *(const short8*)(ptq_w + rb * 1280 + r * 80 + g * 8);
      const short8 pa1 = *(const short8*)(ptq_w + rb * 1280 + r * 80 + 32 + g * 8);
#pragma unroll
      for (int nb = 0; nb < 4; ++nb) {
        o[rb][nb] = mfma16(vv0[nb], pa0, o[rb][nb]);
        o[rb][nb] = mfma16(vv1[nb], pa1, o[rb][nb]);
      }
    }
  }

  // ---- per-wave partials into union region (ptq dead from here) ----
  asm volatile("s_waitcnt lgkmcnt(0)" ::: "memory");
#pragma unroll
  for (int rb = 0; rb < 2; ++rb) {
#pragma unroll
    for (int nb = 0; nb < 4; ++nb)
      *(f32x4*)(po_w + (size_t)(rb * 16 + r) * 68 + nb * 16 + g * 4) = o[rb][nb];
    if (g == 0) {
      pm_w[rb * 16 + r] = m[rb];
      pl_w[rb * 16 + r] = l[rb];
    }
  }
  __syncthreads();
  // ---- merge 8 wave-partials; thread -> (row, 4 cols) ----
  {
    const int tid = threadIdx.x;
    const int row = tid >> 4, cb = (tid & 15) * 4;
    float M = -1e30f;
#pragma unroll
    for (int w = 0; w < 8; ++w)
      M = fmaxf(M, *(const float*)(smem[w] + 8704 + row * 4));
    float scw[8], L = 0.f;
#pragma unroll
    for (int w = 0; w < 8; ++w) {
      scw[w] = exp2a(*(const float*)(smem[w] + 8704 + row * 4) - M);
      L += *(const float*)(smem[w] + 8832 + row * 4) * scw[w];
    }
    const float inv = 1.f / L;
    f32x4 acc = (f32x4)0.f;
#pragma unroll
    for (int w = 0; w < 8; ++w)
      acc += *(const f32x4*)((const float*)smem[w] + (size_t)row * 68 + cb) * scw[w];
    acc *= inv;
    *(f32x4*)(out + ((size_t)b * SEQ + qbase + row) * 64 + cb) = acc;
  }
}

extern "C" void kernel_launch(void* const* d_in, const int* in_sizes, int n_in,
                              void* d_out, int out_size, void* d_ws, size_t ws_size,
                              hipStream_t stream) {
  (void)in_sizes; (void)n_in; (void)out_size; (void)ws_size;
  const float* x  = (const float*)d_in[0];
  const float* wq = (const float*)d_in[1];
  const float* wk = (const float*)d_in[2];
  const float* wv = (const float*)d_in[3];
  float* out = (float*)d_out;

  short* ws  = (short*)d_ws;
  short* wbf = ws;               // 3 * 32768 bf16 (fragment-ordered)
  short* Qs  = ws + 98304;       // 4*4096*64
  short* Ks  = Qs + 1048576;
  short* Vt  = Ks + 1048576;     // transposed V: [4][64][4096]

  wconv_kernel<<<384, 256, 0, stream>>>(wq, wk, wv, wbf);
  proj_kernel<<<768, 256, 0, stream>>>(x, wbf, Qs, Ks, Vt);
  attn_kernel<<<512, 512, 0, stream>>>(Qs, Ks, Vt, out);
}

// Round 8
// 155.112 us; speedup vs baseline: 1.0855x; 1.0855x over previous
//
#include <hip/hip_runtime.h>
#include <hip/hip_bf16.h>
#include <math.h>

typedef short short4v __attribute__((ext_vector_type(4)));
typedef short short8 __attribute__((ext_vector_type(8)));
typedef __bf16 bf16x8 __attribute__((ext_vector_type(8)));
typedef float f32x4 __attribute__((ext_vector_type(4)));

#define SEQ 4096
#define QK_SCALE 0.18033688011112042f  /* (1/8) * log2(e) */

__device__ __forceinline__ short f2bf(float f) {
    __bf16 h = (__bf16)f;
    return __builtin_bit_cast(short, h);
}

__device__ __forceinline__ float exp2a(float x) {  // raw v_exp_f32 (2^x)
    float r;
    asm("v_exp_f32 %0, %1" : "=v"(r) : "v"(x));
    return r;
}

__device__ __forceinline__ f32x4 mfma16(short8 a, short8 b, f32x4 c) {
    return __builtin_amdgcn_mfma_f32_16x16x32_bf16(
        __builtin_bit_cast(bf16x8, a), __builtin_bit_cast(bf16x8, b), c, 0, 0, 0);
}

// ---- kernel 1: W fp32 -> bf16, pre-fragmented for MFMA B-operand. ----
__global__ __launch_bounds__(256) void wconv_kernel(
    const float* __restrict__ wq, const float* __restrict__ wk,
    const float* __restrict__ wv, short* __restrict__ out) {
  int i = blockIdx.x * 256 + threadIdx.x;
  const int j = i & 7, lane = (i >> 3) & 63, nb = (i >> 9) & 3;
  const int t = (i >> 11) & 15, mat = i >> 15;
  const int g = lane >> 4, r = lane & 15;
  const int src = (nb * 16 + r) * 512 + t * 32 + g * 8 + j;
  float v;
  if (mat == 0)      v = wq[src] * QK_SCALE;
  else if (mat == 1) v = wk[src];
  else               v = wv[src];
  out[i] = f2bf(v);
}

// ---- kernel 2: QKV projection (unchanged). ----
__global__ __launch_bounds__(256) void proj_kernel(
    const float* __restrict__ x, const short* __restrict__ wf,
    short* __restrict__ Qs, short* __restrict__ Ks, short* __restrict__ Vt) {
  __shared__ short stg[4][16][72];
  const int bb = blockIdx.x;
  const int mat = bb >> 8, rb = bb & 255;
  const int wave = threadIdx.x >> 6, lane = threadIdx.x & 63;
  const int g = lane >> 4, r = lane & 15;
  const int rbase = rb * 64 + wave * 16;
  const short* wbase = wf + (size_t)mat * 32768;

  f32x4 acc[4];
#pragma unroll
  for (int nb = 0; nb < 4; ++nb) acc[nb] = (f32x4)0.f;

  const float* xp = x + (size_t)(rbase + r) * 512;
#pragma unroll 4
  for (int k0 = 0; k0 < 512; k0 += 32) {
    const int kb = k0 + g * 8;
    f32x4 f0 = *(const f32x4*)(xp + kb);
    f32x4 f1 = *(const f32x4*)(xp + kb + 4);
    short8 a;
    a[0] = f2bf(f0[0]); a[1] = f2bf(f0[1]); a[2] = f2bf(f0[2]); a[3] = f2bf(f0[3]);
    a[4] = f2bf(f1[0]); a[5] = f2bf(f1[1]); a[6] = f2bf(f1[2]); a[7] = f2bf(f1[3]);
    const short* wp = wbase + ((size_t)(k0 >> 5) * 4 * 64 + lane) * 8;
#pragma unroll
    for (int nb = 0; nb < 4; ++nb) {
      short8 bq = *(const short8*)(wp + nb * 512);
      acc[nb] = mfma16(a, bq, acc[nb]);
    }
  }

#pragma unroll
  for (int nb = 0; nb < 4; ++nb) {
#pragma unroll
    for (int reg = 0; reg < 4; ++reg)
      stg[wave][g * 4 + reg][nb * 16 + r] = f2bf(acc[nb][reg]);
  }
  if (mat < 2) {
    short* dst = (mat == 0) ? Qs : Ks;
    const int orow = lane >> 2, ob = lane & 3;
    short8 v0 = *(const short8*)&stg[wave][orow][ob * 8];
    short8 v1 = *(const short8*)&stg[wave][orow][ob * 8 + 32];
    *(short8*)(dst + (size_t)(rbase + orow) * 64 + ob * 8) = v0;
    *(short8*)(dst + (size_t)(rbase + orow) * 64 + ob * 8 + 32) = v1;
  } else {
    const int b = rbase >> 12, sb = rbase & 4095;
    short* vrow = Vt + ((size_t)(b * 64 + lane)) * SEQ + sb;
    short8 v0, v1;
#pragma unroll
    for (int j = 0; j < 8; ++j) v0[j] = stg[wave][j][lane];
#pragma unroll
    for (int j = 0; j < 8; ++j) v1[j] = stg[wave][j + 8][lane];
    *(short8*)(vrow) = v0;
    *(short8*)(vrow + 8) = v1;
  }
}

// ---- kernel 3: flash attention, causal, swapped-operand MFMA.
// 1024 blocks x 256 thr (4 waves): 16 q-rows/block, 4-way KV split.
// Per-wave LDS region 4480 B: ptq (P staging, 2560 B, loop-live) unions
// po/pm/pl (partials after loop). 17.9 KB/block -> 4+ blocks/CU.
// Balanced tile map: CU-coresident blocks' t sums constant. ----
#define REGION 4480
__global__ __launch_bounds__(256) void attn_kernel(
    const short* __restrict__ Qs, const short* __restrict__ Ks,
    const short* __restrict__ Vt, float* __restrict__ out) {
  __shared__ __align__(16) char smem[4][REGION];
  const int blk = blockIdx.x;
  const int b = blk & 3;
  const int idx = blk >> 2;          // [0,256)
  const int jj = idx >> 6, mm = idx & 63;
  const int t = (jj == 0) ? mm : (jj == 1) ? (127 - mm)
              : (jj == 2) ? (128 + mm) : (255 - mm);
  const int wave = threadIdx.x >> 6, lane = threadIdx.x & 63;
  const int g = lane >> 4, r = lane & 15;
  const int qbase = t * 16;
  const short* Qb = Qs + (size_t)b * (SEQ * 64);
  const short* Kb = Ks + (size_t)b * (SEQ * 64);
  const short* Vb = Vt + (size_t)b * (64 * SEQ);

  short* ptq_w = (short*)smem[wave];          // [16][80] shorts (loop)
  float* po_w  = (float*)smem[wave];          // [16][68] floats (after)
  float* pm_w  = (float*)(smem[wave] + 4352); // [16]
  float* pl_w  = (float*)(smem[wave] + 4416); // [16]

  // Q fragment (B-operand: Q[q=r][k])
  const int qoff = (qbase + r) * 64 + g * 8;
  const short8 qf0 = *(const short8*)(Qb + qoff);
  const short8 qf1 = *(const short8*)(Qb + qoff + 32);

  f32x4 o[4];
  float m = -1e30f, l = 0.f;
#pragma unroll
  for (int nb = 0; nb < 4; ++nb) o[nb] = (f32x4)0.f;

  for (int s0 = wave * 64; s0 <= qbase + 15; s0 += 256) {
    // K fragments (A-operand: K[s][k])
    short8 kf0[4], kf1[4];
#pragma unroll
    for (int nc = 0; nc < 4; ++nc) {
      const int koff = (s0 + nc * 16 + r) * 64 + g * 8;
      kf0[nc] = *(const short8*)(Kb + koff);
      kf1[nc] = *(const short8*)(Kb + koff + 32);
    }
    // V fragments (A-operand: Vt[d][s]), hoisted
    short8 vv0[4], vv1[4];
#pragma unroll
    for (int nb = 0; nb < 4; ++nb) {
      const int voff = (nb * 16 + r) * SEQ + s0 + g * 8;
      vv0[nb] = *(const short8*)(Vb + voff);
      vv1[nb] = *(const short8*)(Vb + voff + 32);
    }

    // ---- S^T: D[row=s][col=q]; lane: q=r, s=s0+nc*16+g*4+reg ----
    f32x4 sc[4];
#pragma unroll
    for (int nc = 0; nc < 4; ++nc) {
      sc[nc] = (f32x4)0.f;
      sc[nc] = mfma16(kf0[nc], qf0, sc[nc]);
      sc[nc] = mfma16(kf1[nc], qf1, sc[nc]);
    }
    const int q = qbase + r;
    if (s0 + 63 > qbase) {   // diagonal region: per-element causal mask
#pragma unroll
      for (int nc = 0; nc < 4; ++nc) {
        const int sbase = s0 + nc * 16 + g * 4;
#pragma unroll
        for (int reg = 0; reg < 4; ++reg)
          if (sbase + reg > q) sc[nc][reg] = -1e30f;
      }
    }
    // ---- online softmax: lane-local row + 2 shfl ----
    float mx = fmaxf(fmaxf(sc[0][0], sc[0][1]), fmaxf(sc[0][2], sc[0][3]));
#pragma unroll
    for (int nc = 1; nc < 4; ++nc)
      mx = fmaxf(mx, fmaxf(fmaxf(sc[nc][0], sc[nc][1]), fmaxf(sc[nc][2], sc[nc][3])));
    mx = fmaxf(mx, __shfl_xor(mx, 16));
    mx = fmaxf(mx, __shfl_xor(mx, 32));
    const float mn = fmaxf(m, mx);
    const float fac = exp2a(m - mn);
    m = mn;
    float rs = 0.f;
#pragma unroll
    for (int nc = 0; nc < 4; ++nc) {
#pragma unroll
      for (int reg = 0; reg < 4; ++reg) {
        const float p = exp2a(sc[nc][reg] - mn);
        sc[nc][reg] = p;
        rs += p;
      }
    }
    rs += __shfl_xor(rs, 16);
    rs += __shfl_xor(rs, 32);
    l = l * fac + rs;
#pragma unroll
    for (int nb = 0; nb < 4; ++nb) o[nb] *= fac;
    // ---- P^T -> LDS [q][s] (wave-local) ----
#pragma unroll
    for (int nc = 0; nc < 4; ++nc) {
      short4v p4;
      p4[0] = f2bf(sc[nc][0]); p4[1] = f2bf(sc[nc][1]);
      p4[2] = f2bf(sc[nc][2]); p4[3] = f2bf(sc[nc][3]);
      *(short4v*)(ptq_w + r * 80 + nc * 16 + g * 4) = p4;
    }
    // ---- PV: O^T[d][q] += V^T[d][s] * P^T[s][q] ----
    const short8 pa0 = *(const short8*)(ptq_w + r * 80 + g * 8);
    const short8 pa1 = *(const short8*)(ptq_w + r * 80 + 32 + g * 8);
#pragma unroll
    for (int nb = 0; nb < 4; ++nb) {
      o[nb] = mfma16(vv0[nb], pa0, o[nb]);
      o[nb] = mfma16(vv1[nb], pa1, o[nb]);
    }
  }

  // ---- per-wave partials into union region (ptq dead from here) ----
  asm volatile("s_waitcnt lgkmcnt(0)" ::: "memory");
#pragma unroll
  for (int nb = 0; nb < 4; ++nb)
    *(f32x4*)(po_w + (size_t)r * 68 + nb * 16 + g * 4) = o[nb];
  if (g == 0) {
    pm_w[r] = m;
    pl_w[r] = l;
  }
  __syncthreads();
  // ---- merge 4 wave-partials; thread -> (row, 4 cols) ----
  {
    const int tid = threadIdx.x;
    const int row = tid >> 4, cb = (tid & 15) * 4;
    float M = -1e30f;
#pragma unroll
    for (int w = 0; w < 4; ++w)
      M = fmaxf(M, *(const float*)(smem[w] + 4352 + row * 4));
    float scw[4], L = 0.f;
#pragma unroll
    for (int w = 0; w < 4; ++w) {
      scw[w] = exp2a(*(const float*)(smem[w] + 4352 + row * 4) - M);
      L += *(const float*)(smem[w] + 4416 + row * 4) * scw[w];
    }
    const float inv = 1.f / L;
    f32x4 acc = (f32x4)0.f;
#pragma unroll
    for (int w = 0; w < 4; ++w)
      acc += *(const f32x4*)((const float*)smem[w] + (size_t)row * 68 + cb) * scw[w];
    acc *= inv;
    *(f32x4*)(out + ((size_t)b * SEQ + qbase + row) * 64 + cb) = acc;
  }
}

extern "C" void kernel_launch(void* const* d_in, const int* in_sizes, int n_in,
                              void* d_out, int out_size, void* d_ws, size_t ws_size,
                              hipStream_t stream) {
  (void)in_sizes; (void)n_in; (void)out_size; (void)ws_size;
  const float* x  = (const float*)d_in[0];
  const float* wq = (const float*)d_in[1];
  const float* wk = (const float*)d_in[2];
  const float* wv = (const float*)d_in[3];
  float* out = (float*)d_out;

  short* ws  = (short*)d_ws;
  short* wbf = ws;               // 3 * 32768 bf16 (fragment-ordered)
  short* Qs  = ws + 98304;       // 4*4096*64
  short* Ks  = Qs + 1048576;
  short* Vt  = Ks + 1048576;     // transposed V: [4][64][4096]

  wconv_kernel<<<384, 256, 0, stream>>>(wq, wk, wv, wbf);
  proj_kernel<<<768, 256, 0, stream>>>(x, wbf, Qs, Ks, Vt);
  attn_kernel<<<1024, 256, 0, stream>>>(Qs, Ks, Vt, out);
}

// Round 9
// 128.054 us; speedup vs baseline: 1.3149x; 1.2113x over previous
//
#include <hip/hip_runtime.h>
#include <hip/hip_bf16.h>
#include <math.h>

typedef short short4v __attribute__((ext_vector_type(4)));
typedef short short8 __attribute__((ext_vector_type(8)));
typedef __bf16 bf16x8 __attribute__((ext_vector_type(8)));
typedef float f32x4 __attribute__((ext_vector_type(4)));

#define SEQ 4096
#define QK_SCALE 0.18033688011112042f  /* (1/8) * log2(e) */

__device__ __forceinline__ short f2bf(float f) {
    __bf16 h = (__bf16)f;
    return __builtin_bit_cast(short, h);
}

__device__ __forceinline__ float exp2a(float x) {  // raw v_exp_f32 (2^x)
    float r;
    asm("v_exp_f32 %0, %1" : "=v"(r) : "v"(x));
    return r;
}

__device__ __forceinline__ f32x4 mfma16(short8 a, short8 b, f32x4 c) {
    return __builtin_amdgcn_mfma_f32_16x16x32_bf16(
        __builtin_bit_cast(bf16x8, a), __builtin_bit_cast(bf16x8, b), c, 0, 0, 0);
}

// ---- kernel 1: W fp32 -> bf16, pre-fragmented for MFMA B-operand. ----
__global__ __launch_bounds__(256) void wconv_kernel(
    const float* __restrict__ wq, const float* __restrict__ wk,
    const float* __restrict__ wv, short* __restrict__ out) {
  int i = blockIdx.x * 256 + threadIdx.x;
  const int j = i & 7, lane = (i >> 3) & 63, nb = (i >> 9) & 3;
  const int t = (i >> 11) & 15, mat = i >> 15;
  const int g = lane >> 4, r = lane & 15;
  const int src = (nb * 16 + r) * 512 + t * 32 + g * 8 + j;
  float v;
  if (mat == 0)      v = wq[src] * QK_SCALE;
  else if (mat == 1) v = wk[src];
  else               v = wv[src];
  out[i] = f2bf(v);
}

// ---- kernel 2: QKV projection (unchanged). ----
__global__ __launch_bounds__(256) void proj_kernel(
    const float* __restrict__ x, const short* __restrict__ wf,
    short* __restrict__ Qs, short* __restrict__ Ks, short* __restrict__ Vt) {
  __shared__ short stg[4][16][72];
  const int bb = blockIdx.x;
  const int mat = bb >> 8, rb = bb & 255;
  const int wave = threadIdx.x >> 6, lane = threadIdx.x & 63;
  const int g = lane >> 4, r = lane & 15;
  const int rbase = rb * 64 + wave * 16;
  const short* wbase = wf + (size_t)mat * 32768;

  f32x4 acc[4];
#pragma unroll
  for (int nb = 0; nb < 4; ++nb) acc[nb] = (f32x4)0.f;

  const float* xp = x + (size_t)(rbase + r) * 512;
#pragma unroll 4
  for (int k0 = 0; k0 < 512; k0 += 32) {
    const int kb = k0 + g * 8;
    f32x4 f0 = *(const f32x4*)(xp + kb);
    f32x4 f1 = *(const f32x4*)(xp + kb + 4);
    short8 a;
    a[0] = f2bf(f0[0]); a[1] = f2bf(f0[1]); a[2] = f2bf(f0[2]); a[3] = f2bf(f0[3]);
    a[4] = f2bf(f1[0]); a[5] = f2bf(f1[1]); a[6] = f2bf(f1[2]); a[7] = f2bf(f1[3]);
    const short* wp = wbase + ((size_t)(k0 >> 5) * 4 * 64 + lane) * 8;
#pragma unroll
    for (int nb = 0; nb < 4; ++nb) {
      short8 bq = *(const short8*)(wp + nb * 512);
      acc[nb] = mfma16(a, bq, acc[nb]);
    }
  }

#pragma unroll
  for (int nb = 0; nb < 4; ++nb) {
#pragma unroll
    for (int reg = 0; reg < 4; ++reg)
      stg[wave][g * 4 + reg][nb * 16 + r] = f2bf(acc[nb][reg]);
  }
  if (mat < 2) {
    short* dst = (mat == 0) ? Qs : Ks;
    const int orow = lane >> 2, ob = lane & 3;
    short8 v0 = *(const short8*)&stg[wave][orow][ob * 8];
    short8 v1 = *(const short8*)&stg[wave][orow][ob * 8 + 32];
    *(short8*)(dst + (size_t)(rbase + orow) * 64 + ob * 8) = v0;
    *(short8*)(dst + (size_t)(rbase + orow) * 64 + ob * 8 + 32) = v1;
  } else {
    const int b = rbase >> 12, sb = rbase & 4095;
    short* vrow = Vt + ((size_t)(b * 64 + lane)) * SEQ + sb;
    short8 v0, v1;
#pragma unroll
    for (int j = 0; j < 8; ++j) v0[j] = stg[wave][j][lane];
#pragma unroll
    for (int j = 0; j < 8; ++j) v1[j] = stg[wave][j + 8][lane];
    *(short8*)(vrow) = v0;
    *(short8*)(vrow + 8) = v1;
  }
}

// ---- kernel 3 helpers ----
__device__ __forceinline__ void loadK(const short* __restrict__ Kb, int s0,
                                      int r, int g, short8 (&k0)[4], short8 (&k1)[4]) {
#pragma unroll
  for (int nc = 0; nc < 4; ++nc) {
    const int koff = (s0 + nc * 16 + r) * 64 + g * 8;
    k0[nc] = *(const short8*)(Kb + koff);
    k1[nc] = *(const short8*)(Kb + koff + 32);
  }
}

__device__ __forceinline__ void loadV(const short* __restrict__ Vb, int s0,
                                      int r, int g, short8 (&v0)[4], short8 (&v1)[4]) {
#pragma unroll
  for (int nb = 0; nb < 4; ++nb) {
    const int voff = (nb * 16 + r) * SEQ + s0 + g * 8;
    v0[nb] = *(const short8*)(Vb + voff);
    v1[nb] = *(const short8*)(Vb + voff + 32);
  }
}

__device__ __forceinline__ void computeTile(
    int s0, int qbase, int r, int g, short* __restrict__ ptq_w,
    const short8 (&kf0)[4], const short8 (&kf1)[4],
    const short8 (&vv0)[4], const short8 (&vv1)[4],
    const short8 (&qf)[2][2], f32x4 (&o)[2][4], float (&m)[2], float (&l)[2]) {
#pragma unroll
  for (int rb = 0; rb < 2; ++rb) {
    // S^T: D[row=s][col=q]; lane: q=r, s=s0+nc*16+g*4+reg
    f32x4 sc[4];
#pragma unroll
    for (int nc = 0; nc < 4; ++nc) {
      sc[nc] = (f32x4)0.f;
      sc[nc] = mfma16(kf0[nc], qf[rb][0], sc[nc]);
      sc[nc] = mfma16(kf1[nc], qf[rb][1], sc[nc]);
    }
    const int q = qbase + rb * 16 + r;
    if (s0 + 63 > qbase + rb * 16) {  // wave-uniform: tile touches diagonal
#pragma unroll
      for (int nc = 0; nc < 4; ++nc) {
        const int sbase = s0 + nc * 16 + g * 4;
#pragma unroll
        for (int reg = 0; reg < 4; ++reg)
          if (sbase + reg > q) sc[nc][reg] = -1e30f;
      }
    }
    // online softmax: lane-local row + 2 shfl
    float mx = fmaxf(fmaxf(sc[0][0], sc[0][1]), fmaxf(sc[0][2], sc[0][3]));
#pragma unroll
    for (int nc = 1; nc < 4; ++nc)
      mx = fmaxf(mx, fmaxf(fmaxf(sc[nc][0], sc[nc][1]), fmaxf(sc[nc][2], sc[nc][3])));
    mx = fmaxf(mx, __shfl_xor(mx, 16));
    mx = fmaxf(mx, __shfl_xor(mx, 32));
    const float mn = fmaxf(m[rb], mx);
    const float fac = exp2a(m[rb] - mn);
    m[rb] = mn;
    float rs = 0.f;
#pragma unroll
    for (int nc = 0; nc < 4; ++nc) {
#pragma unroll
      for (int reg = 0; reg < 4; ++reg) {
        const float p = exp2a(sc[nc][reg] - mn);
        sc[nc][reg] = p;
        rs += p;
      }
    }
    rs += __shfl_xor(rs, 16);
    rs += __shfl_xor(rs, 32);
    l[rb] = l[rb] * fac + rs;
#pragma unroll
    for (int nb = 0; nb < 4; ++nb) o[rb][nb] *= fac;
    // P^T -> wave-local LDS [q][s]
#pragma unroll
    for (int nc = 0; nc < 4; ++nc) {
      short4v p4;
      p4[0] = f2bf(sc[nc][0]); p4[1] = f2bf(sc[nc][1]);
      p4[2] = f2bf(sc[nc][2]); p4[3] = f2bf(sc[nc][3]);
      *(short4v*)(ptq_w + rb * 1280 + r * 80 + nc * 16 + g * 4) = p4;
    }
    // PV: O^T[d][q] += V^T[d][s] * P^T[s][q]
    const short8 pa0 = *(const short8*)(ptq_w + rb * 1280 + r * 80 + g * 8);
    const short8 pa1 = *(const short8*)(ptq_w + rb * 1280 + r * 80 + 32 + g * 8);
#pragma unroll
    for (int nb = 0; nb < 4; ++nb) {
      o[rb][nb] = mfma16(vv0[nb], pa0, o[rb][nb]);
      o[rb][nb] = mfma16(vv1[nb], pa1, o[rb][nb]);
    }
  }
}

// ---- kernel 3: flash attention, causal, swapped-operand MFMA.
// 512 blocks x 256 thr (4 waves): 32 q-rows/block, 4-way KV split.
// Register-double-buffered K prefetch (next tile's K issued before current
// softmax); V self-hides (issued at half-iter top, used after softmax).
// Per-wave LDS region 8960 B: ptq (5120 B, loop) unions po/pm/pl (after).
// Paired-balance: blocks i and i+256 (same CU under round-robin) get t, 127-t. ----
#define REGION 8960
__global__ __launch_bounds__(256, 2) void attn_kernel(
    const short* __restrict__ Qs, const short* __restrict__ Ks,
    const short* __restrict__ Vt, float* __restrict__ out) {
  __shared__ __align__(16) char smem[4][REGION];
  const int blk = blockIdx.x;
  const int c = blk & 255, k = blk >> 8;
  const int b = c & 3, tt = c >> 2;
  const int t = k ? tt : (127 - tt);   // pair sums 127
  const int wave = threadIdx.x >> 6, lane = threadIdx.x & 63;
  const int g = lane >> 4, r = lane & 15;
  const int qbase = t * 32;
  const short* Qb = Qs + (size_t)b * (SEQ * 64);
  const short* Kb = Ks + (size_t)b * (SEQ * 64);
  const short* Vb = Vt + (size_t)b * (64 * SEQ);

  short* ptq_w = (short*)smem[wave];          // [2][16][80] shorts (loop)
  float* po_w  = (float*)smem[wave];          // [32][68] floats (after)
  float* pm_w  = (float*)(smem[wave] + 8704); // [32]
  float* pl_w  = (float*)(smem[wave] + 8832); // [32]

  short8 qf[2][2];
#pragma unroll
  for (int rb = 0; rb < 2; ++rb) {
    const int qoff = (qbase + rb * 16 + r) * 64 + g * 8;
    qf[rb][0] = *(const short8*)(Qb + qoff);
    qf[rb][1] = *(const short8*)(Qb + qoff + 32);
  }

  f32x4 o[2][4];
  float m[2] = {-1e30f, -1e30f}, l[2] = {0.f, 0.f};
#pragma unroll
  for (int rb = 0; rb < 2; ++rb)
#pragma unroll
    for (int nb = 0; nb < 4; ++nb) o[rb][nb] = (f32x4)0.f;

  const int qmax = qbase + 31;
  short8 kA0[4], kA1[4], kB0[4], kB1[4], vv0[4], vv1[4];
  {
    int s0 = wave * 64;
    if (s0 <= qmax) {
      loadK(Kb, s0, r, g, kA0, kA1);
      while (true) {
        // --- phase A: compute tile s0 from kA; prefetch K(s0+256) into kB ---
        loadV(Vb, s0, r, g, vv0, vv1);
        int sn = s0 + 256;
        const bool moreA = (sn <= qmax);
        if (moreA) loadK(Kb, sn, r, g, kB0, kB1);
        computeTile(s0, qbase, r, g, ptq_w, kA0, kA1, vv0, vv1, qf, o, m, l);
        if (!moreA) break;
        s0 = sn;
        // --- phase B: compute tile s0 from kB; prefetch K(s0+256) into kA ---
        loadV(Vb, s0, r, g, vv0, vv1);
        sn = s0 + 256;
        const bool moreB = (sn <= qmax);
        if (moreB) loadK(Kb, sn, r, g, kA0, kA1);
        computeTile(s0, qbase, r, g, ptq_w, kB0, kB1, vv0, vv1, qf, o, m, l);
        if (!moreB) break;
        s0 = sn;
      }
    }
  }

  // ---- per-wave partials into union region (ptq dead from here) ----
  asm volatile("s_waitcnt lgkmcnt(0)" ::: "memory");
#pragma unroll
  for (int rb = 0; rb < 2; ++rb) {
#pragma unroll
    for (int nb = 0; nb < 4; ++nb)
      *(f32x4*)(po_w + (size_t)(rb * 16 + r) * 68 + nb * 16 + g * 4) = o[rb][nb];
    if (g == 0) {
      pm_w[rb * 16 + r] = m[rb];
      pl_w[rb * 16 + r] = l[rb];
    }
  }
  __syncthreads();
  // ---- merge 4 wave-partials; thread -> (row, 8 cols) ----
  {
    const int tid = threadIdx.x;
    const int row = tid >> 3, cb = (tid & 7) * 8;
    float M = -1e30f;
#pragma unroll
    for (int w = 0; w < 4; ++w)
      M = fmaxf(M, *(const float*)(smem[w] + 8704 + row * 4));
    float scw[4], L = 0.f;
#pragma unroll
    for (int w = 0; w < 4; ++w) {
      scw[w] = exp2a(*(const float*)(smem[w] + 8704 + row * 4) - M);
      L += *(const float*)(smem[w] + 8832 + row * 4) * scw[w];
    }
    const float inv = 1.f / L;
    f32x4 acc0 = (f32x4)0.f, acc1 = (f32x4)0.f;
#pragma unroll
    for (int w = 0; w < 4; ++w) {
      acc0 += *(const f32x4*)((const float*)smem[w] + (size_t)row * 68 + cb) * scw[w];
      acc1 += *(const f32x4*)((const float*)smem[w] + (size_t)row * 68 + cb + 4) * scw[w];
    }
    acc0 *= inv; acc1 *= inv;
    float* op = out + ((size_t)b * SEQ + qbase + row) * 64 + cb;
    *(f32x4*)op = acc0;
    *(f32x4*)(op + 4) = acc1;
  }
}

extern "C" void kernel_launch(void* const* d_in, const int* in_sizes, int n_in,
                              void* d_out, int out_size, void* d_ws, size_t ws_size,
                              hipStream_t stream) {
  (void)in_sizes; (void)n_in; (void)out_size; (void)ws_size;
  const float* x  = (const float*)d_in[0];
  const float* wq = (const float*)d_in[1];
  const float* wk = (const float*)d_in[2];
  const float* wv = (const float*)d_in[3];
  float* out = (float*)d_out;

  short* ws  = (short*)d_ws;
  short* wbf = ws;               // 3 * 32768 bf16 (fragment-ordered)
  short* Qs  = ws + 98304;       // 4*4096*64
  short* Ks  = Qs + 1048576;
  short* Vt  = Ks + 1048576;     // transposed V: [4][64][4096]

  wconv_kernel<<<384, 256, 0, stream>>>(wq, wk, wv, wbf);
  proj_kernel<<<768, 256, 0, stream>>>(x, wbf, Qs, Ks, Vt);
  attn_kernel<<<512, 256, 0, stream>>>(Qs, Ks, Vt, out);
}